// Round 5
// baseline (350.244 us; speedup 1.0000x reference)
//
#include <hip/hip_runtime.h>

#define F_IN 128
#define H_DIM 64

__device__ __forceinline__ unsigned short f2bf(float f) {
    unsigned int b = __float_as_uint(f);
    b += 0x7fffu + ((b >> 16) & 1u);
    return (unsigned short)(b >> 16);
}
__device__ __forceinline__ float bf2f(unsigned short u) {
    return __uint_as_float((unsigned int)u << 16);
}

// ---------------- GEMM1: hb = bf16(x @ W1)  [N,128]@[128,64] ----------------
// One thread per row, 64 register accumulators, W rows via scalar(uniform) loads.
__global__ __launch_bounds__(256) void gemm1_k(const float* __restrict__ x,
                                               const float* __restrict__ W1,
                                               unsigned short* __restrict__ hb, int N) {
    int r = blockIdx.x * 256 + threadIdx.x;
    if (r >= N) return;
    const float* xr = x + (size_t)r * F_IN;
    float acc[H_DIM];
#pragma unroll
    for (int j = 0; j < H_DIM; ++j) acc[j] = 0.f;
    for (int kc = 0; kc < F_IN; kc += 16) {
        float xv[16];
#pragma unroll
        for (int q = 0; q < 4; ++q) {
            float4 v = *reinterpret_cast<const float4*>(&xr[kc + q * 4]);
            xv[q * 4 + 0] = v.x; xv[q * 4 + 1] = v.y;
            xv[q * 4 + 2] = v.z; xv[q * 4 + 3] = v.w;
        }
#pragma unroll
        for (int kk = 0; kk < 16; ++kk) {
            const float* wrow = &W1[(kc + kk) * H_DIM];
#pragma unroll
            for (int j = 0; j < H_DIM; ++j)
                acc[j] = fmaf(xv[kk], wrow[j], acc[j]);
        }
    }
    unsigned int pk[32];
#pragma unroll
    for (int j = 0; j < 32; ++j)
        pk[j] = (unsigned int)f2bf(acc[2 * j]) | ((unsigned int)f2bf(acc[2 * j + 1]) << 16);
    uint4* dst = reinterpret_cast<uint4*>(hb + (size_t)r * H_DIM);
#pragma unroll
    for (int q = 0; q < 8; ++q)
        dst[q] = make_uint4(pk[4 * q], pk[4 * q + 1], pk[4 * q + 2], pk[4 * q + 3]);
}

// ---------------- GEMM2: z2b = bf16(relu(agg1) @ W2)  [N,64]@[64,64] ----------------
__global__ __launch_bounds__(256) void gemm2_k(const float* __restrict__ agg,
                                               const float* __restrict__ W2,
                                               unsigned short* __restrict__ z2b, int N) {
    int r = blockIdx.x * 256 + threadIdx.x;
    if (r >= N) return;
    const float* ar = agg + (size_t)r * H_DIM;
    float acc[H_DIM];
#pragma unroll
    for (int j = 0; j < H_DIM; ++j) acc[j] = 0.f;
    for (int kc = 0; kc < H_DIM; kc += 16) {
        float xv[16];
#pragma unroll
        for (int q = 0; q < 4; ++q) {
            float4 v = *reinterpret_cast<const float4*>(&ar[kc + q * 4]);
            xv[q * 4 + 0] = fmaxf(v.x, 0.f); xv[q * 4 + 1] = fmaxf(v.y, 0.f);
            xv[q * 4 + 2] = fmaxf(v.z, 0.f); xv[q * 4 + 3] = fmaxf(v.w, 0.f);
        }
#pragma unroll
        for (int kk = 0; kk < 16; ++kk) {
            const float* wrow = &W2[(kc + kk) * H_DIM];
#pragma unroll
            for (int j = 0; j < H_DIM; ++j)
                acc[j] = fmaf(xv[kk], wrow[j], acc[j]);
        }
    }
    unsigned int pk[32];
#pragma unroll
    for (int j = 0; j < 32; ++j)
        pk[j] = (unsigned int)f2bf(acc[2 * j]) | ((unsigned int)f2bf(acc[2 * j + 1]) << 16);
    uint4* dst = reinterpret_cast<uint4*>(z2b + (size_t)r * H_DIM);
#pragma unroll
    for (int q = 0; q < 8; ++q)
        dst[q] = make_uint4(pk[4 * q], pk[4 * q + 1], pk[4 * q + 2], pk[4 * q + 3]);
}

// ---------------- CSR build ----------------
__global__ __launch_bounds__(256) void count_k(const int* __restrict__ ei, int* __restrict__ deg, int E) {
    int e = blockIdx.x * 256 + threadIdx.x;
    if (e < E) atomicAdd(&deg[ei[E + e]], 1);
}

__global__ __launch_bounds__(256) void scan1_k(const int* __restrict__ deg, int* __restrict__ blocksum, int N) {
    __shared__ int ls[4];
    int i = blockIdx.x * 256 + threadIdx.x;
    int v = (i < N) ? deg[i] : 0;
#pragma unroll
    for (int off = 32; off > 0; off >>= 1) v += __shfl_down(v, off);
    int wid = threadIdx.x >> 6;
    if ((threadIdx.x & 63) == 0) ls[wid] = v;
    __syncthreads();
    if (threadIdx.x == 0) blocksum[blockIdx.x] = ls[0] + ls[1] + ls[2] + ls[3];
}

__global__ __launch_bounds__(512) void scan2_k(const int* __restrict__ blocksum, int* __restrict__ blockoff, int NB) {
    __shared__ int s[512];
    int t = threadIdx.x;
    int v = (t < NB) ? blocksum[t] : 0;
    s[t] = v;
    __syncthreads();
    for (int off = 1; off < 512; off <<= 1) {
        int add = (t >= off) ? s[t - off] : 0;
        __syncthreads();
        s[t] += add;
        __syncthreads();
    }
    if (t < NB) blockoff[t] = s[t] - v;  // exclusive
}

__global__ __launch_bounds__(256) void scan3_k(const int* __restrict__ deg, const int* __restrict__ blockoff,
                                               int* __restrict__ rowptr, int N) {
    __shared__ int s[256];
    int t = threadIdx.x;
    int i = blockIdx.x * 256 + t;
    int v = (i < N) ? deg[i] : 0;
    s[t] = v;
    __syncthreads();
    for (int off = 1; off < 256; off <<= 1) {
        int add = (t >= off) ? s[t - off] : 0;
        __syncthreads();
        s[t] += add;
        __syncthreads();
    }
    if (i < N) rowptr[i] = s[t] - v + blockoff[blockIdx.x];
}

// fill: plain nontemporal 8B store (atomicExch regressed: line write-back is
// 64B-granular for ALL scattered stores; atomics just add L2 serialization).
__global__ __launch_bounds__(256) void fill_k(const int* __restrict__ ei, const float* __restrict__ w,
                                              const int* __restrict__ rowptr, int* __restrict__ cursor,
                                              unsigned long long* __restrict__ epack, int E) {
    int e = blockIdx.x * 256 + threadIdx.x;
    if (e >= E) return;
    int d = ei[E + e];
    int slot = rowptr[d] + atomicAdd(&cursor[d], 1);
    unsigned long long val = ((unsigned long long)__float_as_uint(w[e]) << 32) | (unsigned int)ei[e];
    __builtin_nontemporal_store(val, &epack[slot]);
}

// ---------------- agg1: out[n,:] = sum_j w_j * bf2f(hb[src_j,:])  (wave per node) ----------------
__global__ __launch_bounds__(256) void agg1_k(const unsigned short* __restrict__ hb,
                                              const int* __restrict__ rowptr, const int* __restrict__ deg,
                                              const int2* __restrict__ epack,
                                              float* __restrict__ out, int N) {
    int node = blockIdx.x * 4 + (threadIdx.x >> 6);
    if (node >= N) return;
    int lane = threadIdx.x & 63;
    int start = rowptr[node];
    int cnt = deg[node];
    float acc0 = 0.f, acc1 = 0.f, acc2 = 0.f, acc3 = 0.f;
    int j = 0;
    for (; j + 3 < cnt; j += 4) {
        int2 p0 = epack[start + j];
        int2 p1 = epack[start + j + 1];
        int2 p2 = epack[start + j + 2];
        int2 p3 = epack[start + j + 3];
        acc0 = fmaf(__int_as_float(p0.y), bf2f(hb[(size_t)p0.x * H_DIM + lane]), acc0);
        acc1 = fmaf(__int_as_float(p1.y), bf2f(hb[(size_t)p1.x * H_DIM + lane]), acc1);
        acc2 = fmaf(__int_as_float(p2.y), bf2f(hb[(size_t)p2.x * H_DIM + lane]), acc2);
        acc3 = fmaf(__int_as_float(p3.y), bf2f(hb[(size_t)p3.x * H_DIM + lane]), acc3);
    }
    for (; j < cnt; ++j) {
        int2 p0 = epack[start + j];
        acc0 = fmaf(__int_as_float(p0.y), bf2f(hb[(size_t)p0.x * H_DIM + lane]), acc0);
    }
    out[(size_t)node * H_DIM + lane] = (acc0 + acc1) + (acc2 + acc3);
}

// ---------------- agg2 + fused projection: u[n] = (z·A0, z·A1, z·B0, z·B1) ----------------
// z[n] never materialized: lane holds z[n][lane], 4 butterfly reduces -> float4 u.
__global__ __launch_bounds__(256) void agg2p_k(const unsigned short* __restrict__ z2b,
                                               const int* __restrict__ rowptr, const int* __restrict__ deg,
                                               const int2* __restrict__ epack,
                                               const float* __restrict__ Wlin,  // [2,128]
                                               float4* __restrict__ u, int N) {
    int node = blockIdx.x * 4 + (threadIdx.x >> 6);
    if (node >= N) return;
    int lane = threadIdx.x & 63;
    int start = rowptr[node];
    int cnt = deg[node];
    float acc0 = 0.f, acc1 = 0.f, acc2 = 0.f, acc3 = 0.f;
    int j = 0;
    for (; j + 3 < cnt; j += 4) {
        int2 p0 = epack[start + j];
        int2 p1 = epack[start + j + 1];
        int2 p2 = epack[start + j + 2];
        int2 p3 = epack[start + j + 3];
        acc0 = fmaf(__int_as_float(p0.y), bf2f(z2b[(size_t)p0.x * H_DIM + lane]), acc0);
        acc1 = fmaf(__int_as_float(p1.y), bf2f(z2b[(size_t)p1.x * H_DIM + lane]), acc1);
        acc2 = fmaf(__int_as_float(p2.y), bf2f(z2b[(size_t)p2.x * H_DIM + lane]), acc2);
        acc3 = fmaf(__int_as_float(p3.y), bf2f(z2b[(size_t)p3.x * H_DIM + lane]), acc3);
    }
    for (; j < cnt; ++j) {
        int2 p0 = epack[start + j];
        acc0 = fmaf(__int_as_float(p0.y), bf2f(z2b[(size_t)p0.x * H_DIM + lane]), acc0);
    }
    float zl = (acc0 + acc1) + (acc2 + acc3);   // z[node][lane]
    float p0 = zl * Wlin[lane];          // row0 first half  (A0)
    float p1 = zl * Wlin[128 + lane];    // row1 first half  (A1)
    float p2 = zl * Wlin[64 + lane];     // row0 second half (B0)
    float p3 = zl * Wlin[192 + lane];    // row1 second half (B1)
#pragma unroll
    for (int m = 32; m > 0; m >>= 1) {
        p0 += __shfl_xor(p0, m);
        p1 += __shfl_xor(p1, m);
        p2 += __shfl_xor(p2, m);
        p3 += __shfl_xor(p3, m);
    }
    if (lane == 0) u[node] = make_float4(p0, p1, p2, p3);
}

// ---------------- pair decode ----------------
__global__ __launch_bounds__(256) void pair_k(const float4* __restrict__ u,
                                              const int* __restrict__ pos,  // [2,P] flat
                                              float2* __restrict__ out, int P) {
    int p = blockIdx.x * 256 + threadIdx.x;
    if (p >= P) return;
    int s = pos[p];
    int t = pos[P + p];
    float4 us = u[s];
    float4 ut = u[t];
    out[p] = make_float2(us.x + ut.z, us.y + ut.w);
}

extern "C" void kernel_launch(void* const* d_in, const int* in_sizes, int n_in,
                              void* d_out, int out_size, void* d_ws, size_t ws_size,
                              hipStream_t stream) {
    const float* x    = (const float*)d_in[0];
    const int*   ei   = (const int*)d_in[1];    // [2,E]
    const float* ew   = (const float*)d_in[2];  // [E]
    const int*   pos  = (const int*)d_in[3];    // [2,P]
    const float* W1   = (const float*)d_in[4];  // [128,64]
    const float* W2   = (const float*)d_in[5];  // [64,64]
    const float* Wlin = (const float*)d_in[6];  // [2,128]
    float* out = (float*)d_out;

    const int N = in_sizes[0] / F_IN;      // 100000
    const int E = in_sizes[2];             // 1000000
    const int P = in_sizes[3] / 2;         // 500000
    const int NB = (N + 255) / 256;        // 391

    // workspace layout (bytes)
    char* ws = (char*)d_ws;
    const size_t rowF32 = (size_t)N * H_DIM * sizeof(float);          // 25.6 MB
    const size_t rowBF  = (size_t)N * H_DIM * sizeof(unsigned short); // 12.8 MB
    float*          A1    = (float*)ws;                       // agg1 out (f32)
    unsigned short* hb    = (unsigned short*)(ws + rowF32);   // gemm1 out (bf16)
    unsigned short* z2b   = (unsigned short*)(ws + rowF32 + rowBF);   // gemm2 out (bf16)
    float4*         u     = (float4*)(ws + rowF32 + 2 * rowBF);       // N float4
    unsigned long long* epack = (unsigned long long*)(ws + rowF32 + 2 * rowBF + (size_t)N * 16);
    int* deg      = (int*)((char*)epack + (size_t)E * 8);
    int* rowptr   = deg + N;
    int* cursor   = rowptr + N;
    int* blocksum = cursor + N;
    int* blockoff = blocksum + NB;

    // conv1 matmul -> hb (bf16)
    gemm1_k<<<(N + 255) / 256, 256, 0, stream>>>(x, W1, hb, N);

    // CSR build (once; reused by both aggregations)
    hipMemsetAsync(deg, 0, (size_t)N * sizeof(int), stream);
    hipMemsetAsync(cursor, 0, (size_t)N * sizeof(int), stream);
    count_k<<<(E + 255) / 256, 256, 0, stream>>>(ei, deg, E);
    scan1_k<<<NB, 256, 0, stream>>>(deg, blocksum, N);
    scan2_k<<<1, 512, 0, stream>>>(blocksum, blockoff, NB);
    scan3_k<<<NB, 256, 0, stream>>>(deg, blockoff, rowptr, N);
    fill_k<<<(E + 255) / 256, 256, 0, stream>>>(ei, ew, rowptr, cursor, epack, E);

    // agg1: hb -> A1 (f32)
    agg1_k<<<(N + 3) / 4, 256, 0, stream>>>(hb, rowptr, deg, (const int2*)epack, A1, N);
    // conv2 matmul (relu fused on input): A1 -> z2b (bf16)
    gemm2_k<<<(N + 255) / 256, 256, 0, stream>>>(A1, W2, z2b, N);
    // agg2 + fused projection: z2b -> u
    agg2p_k<<<(N + 3) / 4, 256, 0, stream>>>(z2b, rowptr, deg, (const int2*)epack, Wlin, u, N);
    // pair decode
    pair_k<<<(P + 255) / 256, 256, 0, stream>>>(u, pos, (float2*)out, P);
}

// Round 6
// 267.216 us; speedup vs baseline: 1.3107x; 1.3107x over previous
//
#include <hip/hip_runtime.h>

#define F_IN 128
#define H_DIM 64

typedef short s16x8 __attribute__((ext_vector_type(8)));
typedef float f32x4 __attribute__((ext_vector_type(4)));

union FragU {
    s16x8 s;
    uint4 q;
    unsigned short u[8];
};

__device__ __forceinline__ unsigned short f2bf(float f) {
    unsigned int b = __float_as_uint(f);
    b += 0x7fffu + ((b >> 16) & 1u);
    return (unsigned short)(b >> 16);
}
__device__ __forceinline__ float bf2f(unsigned short u) {
    return __uint_as_float((unsigned int)u << 16);
}

// ---------------- W prepack: W[K x 64] f32 -> B-fragments bf16 ----------------
// Fragment layout for mfma_f32_16x16x32_bf16 operand B[k][j]:
//   lane = j + 16*(k/8), elem = k%8.  Stored per (coltile ct, kstep ks):
//   wf[((ct*KS+ks)*64 + lane)*8 + elem], 16B per lane -> coalesced uint4 reads.
__global__ __launch_bounds__(256) void prepack_k(const float* __restrict__ W,
                                                 unsigned short* __restrict__ wf, int K) {
    int KS = K / 32;
    int total = 4 * KS * 64;
    int tid = blockIdx.x * 256 + threadIdx.x;
    if (tid >= total) return;
    int lane = tid & 63;
    int grp = tid >> 6;
    int ks = grp % KS;
    int ct = grp / KS;
    int col = ct * 16 + (lane & 15);
    int kbase = ks * 32 + (lane >> 4) * 8;
    FragU f;
#pragma unroll
    for (int j = 0; j < 8; ++j) f.u[j] = f2bf(W[(kbase + j) * H_DIM + col]);
    reinterpret_cast<uint4*>(wf)[tid] = f.q;
}

// ---------------- MFMA GEMM: outb = bf16(A @ W) [N x K]@[K x 64] ----------------
// Wave computes 16 rows x 64 cols. A from global (f32 converted inline if CONV,
// else bf16); B from prepacked fragments (L1-resident). No LDS.
template <int K, bool CONV>
__global__ __launch_bounds__(256) void mfma_gemm_k(const void* __restrict__ Ain,
                                                   const unsigned short* __restrict__ wf,
                                                   unsigned short* __restrict__ outb, int N) {
    constexpr int KS = K / 32;
    int wv = threadIdx.x >> 6;
    int lane = threadIdx.x & 63;
    int rb = blockIdx.x * 64 + wv * 16;
    int ra = rb + (lane & 15);
    if (ra > N - 1) ra = N - 1;           // clamp loads; stores guarded below
    int koct = lane >> 4;

    FragU af[KS];
    if (CONV) {
        const float* ap = (const float*)Ain + (size_t)ra * K + koct * 8;
#pragma unroll
        for (int ks = 0; ks < KS; ++ks) {
            float4 v0 = *reinterpret_cast<const float4*>(ap + ks * 32);
            float4 v1 = *reinterpret_cast<const float4*>(ap + ks * 32 + 4);
            af[ks].u[0] = f2bf(v0.x); af[ks].u[1] = f2bf(v0.y);
            af[ks].u[2] = f2bf(v0.z); af[ks].u[3] = f2bf(v0.w);
            af[ks].u[4] = f2bf(v1.x); af[ks].u[5] = f2bf(v1.y);
            af[ks].u[6] = f2bf(v1.z); af[ks].u[7] = f2bf(v1.w);
        }
    } else {
        const unsigned short* ap = (const unsigned short*)Ain + (size_t)ra * K + koct * 8;
#pragma unroll
        for (int ks = 0; ks < KS; ++ks)
            af[ks].q = *reinterpret_cast<const uint4*>(ap + ks * 32);
    }

    const uint4* bq = reinterpret_cast<const uint4*>(wf);
    f32x4 acc[4];
#pragma unroll
    for (int ct = 0; ct < 4; ++ct) acc[ct] = (f32x4){0.f, 0.f, 0.f, 0.f};
#pragma unroll
    for (int ct = 0; ct < 4; ++ct) {
#pragma unroll
        for (int ks = 0; ks < KS; ++ks) {
            FragU b;
            b.q = bq[(ct * KS + ks) * 64 + lane];
            acc[ct] = __builtin_amdgcn_mfma_f32_16x16x32_bf16(af[ks].s, b.s, acc[ct], 0, 0, 0);
        }
    }

    // C/D layout: col = lane&15, row = (lane>>4)*4 + reg  (verified m89)
    int ro_base = rb + (lane >> 4) * 4;
    int col = lane & 15;
#pragma unroll
    for (int ct = 0; ct < 4; ++ct) {
#pragma unroll
        for (int j = 0; j < 4; ++j) {
            int ro = ro_base + j;
            if (ro < N) outb[(size_t)ro * H_DIM + ct * 16 + col] = f2bf(acc[ct][j]);
        }
    }
}

// ---------------- CSR build ----------------
__global__ __launch_bounds__(256) void count_k(const int* __restrict__ ei, int* __restrict__ deg, int E) {
    int e = blockIdx.x * 256 + threadIdx.x;
    if (e < E) atomicAdd(&deg[ei[E + e]], 1);
}

__global__ __launch_bounds__(256) void scan1_k(const int* __restrict__ deg, int* __restrict__ blocksum, int N) {
    __shared__ int ls[4];
    int i = blockIdx.x * 256 + threadIdx.x;
    int v = (i < N) ? deg[i] : 0;
#pragma unroll
    for (int off = 32; off > 0; off >>= 1) v += __shfl_down(v, off);
    int wid = threadIdx.x >> 6;
    if ((threadIdx.x & 63) == 0) ls[wid] = v;
    __syncthreads();
    if (threadIdx.x == 0) blocksum[blockIdx.x] = ls[0] + ls[1] + ls[2] + ls[3];
}

__global__ __launch_bounds__(512) void scan2_k(const int* __restrict__ blocksum, int* __restrict__ blockoff, int NB) {
    __shared__ int s[512];
    int t = threadIdx.x;
    int v = (t < NB) ? blocksum[t] : 0;
    s[t] = v;
    __syncthreads();
    for (int off = 1; off < 512; off <<= 1) {
        int add = (t >= off) ? s[t - off] : 0;
        __syncthreads();
        s[t] += add;
        __syncthreads();
    }
    if (t < NB) blockoff[t] = s[t] - v;  // exclusive
}

__global__ __launch_bounds__(256) void scan3_k(const int* __restrict__ deg, const int* __restrict__ blockoff,
                                               int* __restrict__ rowptr, int N) {
    __shared__ int s[256];
    int t = threadIdx.x;
    int i = blockIdx.x * 256 + t;
    int v = (i < N) ? deg[i] : 0;
    s[t] = v;
    __syncthreads();
    for (int off = 1; off < 256; off <<= 1) {
        int add = (t >= off) ? s[t - off] : 0;
        __syncthreads();
        s[t] += add;
        __syncthreads();
    }
    if (i < N) rowptr[i] = s[t] - v + blockoff[blockIdx.x];
}

__global__ __launch_bounds__(256) void fill_k(const int* __restrict__ ei, const float* __restrict__ w,
                                              const int* __restrict__ rowptr, int* __restrict__ cursor,
                                              unsigned long long* __restrict__ epack, int E) {
    int e = blockIdx.x * 256 + threadIdx.x;
    if (e >= E) return;
    int d = ei[E + e];
    int slot = rowptr[d] + atomicAdd(&cursor[d], 1);
    unsigned long long val = ((unsigned long long)__float_as_uint(w[e]) << 32) | (unsigned int)ei[e];
    __builtin_nontemporal_store(val, &epack[slot]);
}

// ---------------- agg1: outb[n,:] = bf16(relu(sum_j w_j * bf2f(hb[src_j,:]))) ----------------
__global__ __launch_bounds__(256) void agg1_k(const unsigned short* __restrict__ hb,
                                              const int* __restrict__ rowptr, const int* __restrict__ deg,
                                              const int2* __restrict__ epack,
                                              unsigned short* __restrict__ outb, int N) {
    int node = blockIdx.x * 4 + (threadIdx.x >> 6);
    if (node >= N) return;
    int lane = threadIdx.x & 63;
    int start = rowptr[node];
    int cnt = deg[node];
    float acc0 = 0.f, acc1 = 0.f, acc2 = 0.f, acc3 = 0.f;
    int j = 0;
    for (; j + 3 < cnt; j += 4) {
        int2 p0 = epack[start + j];
        int2 p1 = epack[start + j + 1];
        int2 p2 = epack[start + j + 2];
        int2 p3 = epack[start + j + 3];
        acc0 = fmaf(__int_as_float(p0.y), bf2f(hb[(size_t)p0.x * H_DIM + lane]), acc0);
        acc1 = fmaf(__int_as_float(p1.y), bf2f(hb[(size_t)p1.x * H_DIM + lane]), acc1);
        acc2 = fmaf(__int_as_float(p2.y), bf2f(hb[(size_t)p2.x * H_DIM + lane]), acc2);
        acc3 = fmaf(__int_as_float(p3.y), bf2f(hb[(size_t)p3.x * H_DIM + lane]), acc3);
    }
    for (; j < cnt; ++j) {
        int2 p0 = epack[start + j];
        acc0 = fmaf(__int_as_float(p0.y), bf2f(hb[(size_t)p0.x * H_DIM + lane]), acc0);
    }
    float total = (acc0 + acc1) + (acc2 + acc3);
    outb[(size_t)node * H_DIM + lane] = f2bf(fmaxf(total, 0.f));  // relu fused (pre-gemm2)
}

// ---------------- agg2 + fused projection: u[n] = (z·A0, z·A1, z·B0, z·B1) ----------------
__global__ __launch_bounds__(256) void agg2p_k(const unsigned short* __restrict__ z2b,
                                               const int* __restrict__ rowptr, const int* __restrict__ deg,
                                               const int2* __restrict__ epack,
                                               const float* __restrict__ Wlin,  // [2,128]
                                               float4* __restrict__ u, int N) {
    int node = blockIdx.x * 4 + (threadIdx.x >> 6);
    if (node >= N) return;
    int lane = threadIdx.x & 63;
    int start = rowptr[node];
    int cnt = deg[node];
    float acc0 = 0.f, acc1 = 0.f, acc2 = 0.f, acc3 = 0.f;
    int j = 0;
    for (; j + 3 < cnt; j += 4) {
        int2 p0 = epack[start + j];
        int2 p1 = epack[start + j + 1];
        int2 p2 = epack[start + j + 2];
        int2 p3 = epack[start + j + 3];
        acc0 = fmaf(__int_as_float(p0.y), bf2f(z2b[(size_t)p0.x * H_DIM + lane]), acc0);
        acc1 = fmaf(__int_as_float(p1.y), bf2f(z2b[(size_t)p1.x * H_DIM + lane]), acc1);
        acc2 = fmaf(__int_as_float(p2.y), bf2f(z2b[(size_t)p2.x * H_DIM + lane]), acc2);
        acc3 = fmaf(__int_as_float(p3.y), bf2f(z2b[(size_t)p3.x * H_DIM + lane]), acc3);
    }
    for (; j < cnt; ++j) {
        int2 p0 = epack[start + j];
        acc0 = fmaf(__int_as_float(p0.y), bf2f(z2b[(size_t)p0.x * H_DIM + lane]), acc0);
    }
    float zl = (acc0 + acc1) + (acc2 + acc3);   // z[node][lane]
    float p0 = zl * Wlin[lane];          // row0 first half  (A0)
    float p1 = zl * Wlin[128 + lane];    // row1 first half  (A1)
    float p2 = zl * Wlin[64 + lane];     // row0 second half (B0)
    float p3 = zl * Wlin[192 + lane];    // row1 second half (B1)
#pragma unroll
    for (int m = 32; m > 0; m >>= 1) {
        p0 += __shfl_xor(p0, m);
        p1 += __shfl_xor(p1, m);
        p2 += __shfl_xor(p2, m);
        p3 += __shfl_xor(p3, m);
    }
    if (lane == 0) u[node] = make_float4(p0, p1, p2, p3);
}

// ---------------- pair decode ----------------
__global__ __launch_bounds__(256) void pair_k(const float4* __restrict__ u,
                                              const int* __restrict__ pos,  // [2,P] flat
                                              float2* __restrict__ out, int P) {
    int p = blockIdx.x * 256 + threadIdx.x;
    if (p >= P) return;
    int s = pos[p];
    int t = pos[P + p];
    float4 us = u[s];
    float4 ut = u[t];
    out[p] = make_float2(us.x + ut.z, us.y + ut.w);
}

extern "C" void kernel_launch(void* const* d_in, const int* in_sizes, int n_in,
                              void* d_out, int out_size, void* d_ws, size_t ws_size,
                              hipStream_t stream) {
    const float* x    = (const float*)d_in[0];
    const int*   ei   = (const int*)d_in[1];    // [2,E]
    const float* ew   = (const float*)d_in[2];  // [E]
    const int*   pos  = (const int*)d_in[3];    // [2,P]
    const float* W1   = (const float*)d_in[4];  // [128,64]
    const float* W2   = (const float*)d_in[5];  // [64,64]
    const float* Wlin = (const float*)d_in[6];  // [2,128]
    float* out = (float*)d_out;

    const int N = in_sizes[0] / F_IN;      // 100000
    const int E = in_sizes[2];             // 1000000
    const int P = in_sizes[3] / 2;         // 500000
    const int NB = (N + 255) / 256;        // 391

    // workspace layout (bytes)
    char* ws = (char*)d_ws;
    const size_t rowBF = (size_t)N * H_DIM * sizeof(unsigned short);  // 12.8 MB
    unsigned short* hb   = (unsigned short*)ws;                // gemm1 out (bf16)
    unsigned short* a1b  = (unsigned short*)(ws + rowBF);      // relu(agg1) (bf16)
    unsigned short* z2b  = (unsigned short*)(ws + 2 * rowBF);  // gemm2 out (bf16)
    float4*         u    = (float4*)(ws + 3 * rowBF);          // N float4
    unsigned long long* epack = (unsigned long long*)(ws + 3 * rowBF + (size_t)N * 16);
    int* deg      = (int*)((char*)epack + (size_t)E * 8);
    int* rowptr   = deg + N;
    int* cursor   = rowptr + N;
    int* blocksum = cursor + N;
    int* blockoff = blocksum + NB;
    // 16B-aligned prepacked weight fragments
    size_t wf_off = (((size_t)((char*)(blockoff + NB) - ws)) + 15) & ~(size_t)15;
    unsigned short* wf1 = (unsigned short*)(ws + wf_off);      // 4*4*64*8 bf16 = 16 KB
    unsigned short* wf2 = wf1 + 4 * 4 * 64 * 8;                // 4*2*64*8 bf16 = 8 KB

    // weight prepack (tiny)
    prepack_k<<<4, 256, 0, stream>>>(W1, wf1, F_IN);
    prepack_k<<<2, 256, 0, stream>>>(W2, wf2, H_DIM);

    // conv1 matmul (x f32 converted to bf16 in-register) -> hb
    mfma_gemm_k<F_IN, true><<<(N + 63) / 64, 256, 0, stream>>>(x, wf1, hb, N);

    // CSR build (once; reused by both aggregations)
    hipMemsetAsync(deg, 0, (size_t)N * sizeof(int), stream);
    hipMemsetAsync(cursor, 0, (size_t)N * sizeof(int), stream);
    count_k<<<(E + 255) / 256, 256, 0, stream>>>(ei, deg, E);
    scan1_k<<<NB, 256, 0, stream>>>(deg, blocksum, N);
    scan2_k<<<1, 512, 0, stream>>>(blocksum, blockoff, NB);
    scan3_k<<<NB, 256, 0, stream>>>(deg, blockoff, rowptr, N);
    fill_k<<<(E + 255) / 256, 256, 0, stream>>>(ei, ew, rowptr, cursor, epack, E);

    // agg1: hb -> a1b (bf16, relu fused)
    agg1_k<<<(N + 3) / 4, 256, 0, stream>>>(hb, rowptr, deg, (const int2*)epack, a1b, N);
    // conv2 matmul: a1b -> z2b
    mfma_gemm_k<H_DIM, false><<<(N + 63) / 64, 256, 0, stream>>>(a1b, wf2, z2b, N);
    // agg2 + fused projection: z2b -> u
    agg2p_k<<<(N + 3) / 4, 256, 0, stream>>>(z2b, rowptr, deg, (const int2*)epack, Wlin, u, N);
    // pair decode
    pair_k<<<(P + 255) / 256, 256, 0, stream>>>(u, pos, (float2*)out, P);
}

// Round 7
// 188.974 us; speedup vs baseline: 1.8534x; 1.4140x over previous
//
#include <hip/hip_runtime.h>

#define F_IN 128
#define H_DIM 64
#define NBUCK_MAX 1024   // buckets of 128 nodes; N <= 131072

typedef short s16x8 __attribute__((ext_vector_type(8)));
typedef float f32x4 __attribute__((ext_vector_type(4)));

union FragU {
    s16x8 s;
    uint4 q;
    unsigned short u[8];
};

__device__ __forceinline__ unsigned short f2bf(float f) {
    unsigned int b = __float_as_uint(f);
    b += 0x7fffu + ((b >> 16) & 1u);
    return (unsigned short)(b >> 16);
}
__device__ __forceinline__ float bf2f(unsigned short u) {
    return __uint_as_float((unsigned int)u << 16);
}

// ---------------- W prepack: W[K x 64] f32 -> B-fragments bf16 ----------------
__global__ __launch_bounds__(256) void prepack_k(const float* __restrict__ W,
                                                 unsigned short* __restrict__ wf, int K) {
    int KS = K / 32;
    int total = 4 * KS * 64;
    int tid = blockIdx.x * 256 + threadIdx.x;
    if (tid >= total) return;
    int lane = tid & 63;
    int grp = tid >> 6;
    int ks = grp % KS;
    int ct = grp / KS;
    int col = ct * 16 + (lane & 15);
    int kbase = ks * 32 + (lane >> 4) * 8;
    FragU f;
#pragma unroll
    for (int j = 0; j < 8; ++j) f.u[j] = f2bf(W[(kbase + j) * H_DIM + col]);
    reinterpret_cast<uint4*>(wf)[tid] = f.q;
}

// ---------------- MFMA GEMM: outb = bf16(A @ W) [N x K]@[K x 64] ----------------
template <int K, bool CONV>
__global__ __launch_bounds__(256) void mfma_gemm_k(const void* __restrict__ Ain,
                                                   const unsigned short* __restrict__ wf,
                                                   unsigned short* __restrict__ outb, int N) {
    constexpr int KS = K / 32;
    int wv = threadIdx.x >> 6;
    int lane = threadIdx.x & 63;
    int rb = blockIdx.x * 64 + wv * 16;
    int ra = rb + (lane & 15);
    if (ra > N - 1) ra = N - 1;
    int koct = lane >> 4;

    FragU af[KS];
    if (CONV) {
        const float* ap = (const float*)Ain + (size_t)ra * K + koct * 8;
#pragma unroll
        for (int ks = 0; ks < KS; ++ks) {
            float4 v0 = *reinterpret_cast<const float4*>(ap + ks * 32);
            float4 v1 = *reinterpret_cast<const float4*>(ap + ks * 32 + 4);
            af[ks].u[0] = f2bf(v0.x); af[ks].u[1] = f2bf(v0.y);
            af[ks].u[2] = f2bf(v0.z); af[ks].u[3] = f2bf(v0.w);
            af[ks].u[4] = f2bf(v1.x); af[ks].u[5] = f2bf(v1.y);
            af[ks].u[6] = f2bf(v1.z); af[ks].u[7] = f2bf(v1.w);
        }
    } else {
        const unsigned short* ap = (const unsigned short*)Ain + (size_t)ra * K + koct * 8;
#pragma unroll
        for (int ks = 0; ks < KS; ++ks)
            af[ks].q = *reinterpret_cast<const uint4*>(ap + ks * 32);
    }

    const uint4* bq = reinterpret_cast<const uint4*>(wf);
    f32x4 acc[4];
#pragma unroll
    for (int ct = 0; ct < 4; ++ct) acc[ct] = (f32x4){0.f, 0.f, 0.f, 0.f};
#pragma unroll
    for (int ct = 0; ct < 4; ++ct) {
#pragma unroll
        for (int ks = 0; ks < KS; ++ks) {
            FragU b;
            b.q = bq[(ct * KS + ks) * 64 + lane];
            acc[ct] = __builtin_amdgcn_mfma_f32_16x16x32_bf16(af[ks].s, b.s, acc[ct], 0, 0, 0);
        }
    }

    int ro_base = rb + (lane >> 4) * 4;
    int col = lane & 15;
#pragma unroll
    for (int ct = 0; ct < 4; ++ct) {
#pragma unroll
        for (int j = 0; j < 4; ++j) {
            int ro = ro_base + j;
            if (ro < N) outb[(size_t)ro * H_DIM + ct * 16 + col] = f2bf(acc[ct][j]);
        }
    }
}

// ---------------- binning sort: global bucket histogram ----------------
__global__ __launch_bounds__(256) void ghist_k(const int* __restrict__ ei,
                                               int* __restrict__ ghist, int E, int nbuck) {
    __shared__ int h[NBUCK_MAX];
    int tid = threadIdx.x;
    for (int i = tid; i < nbuck; i += 256) h[i] = 0;
    __syncthreads();
    int e0 = blockIdx.x * 8192;
    int ecount = min(8192, E - e0);
    for (int i = tid; i < ecount; i += 256)
        atomicAdd(&h[ei[E + e0 + i] >> 7], 1);
    __syncthreads();
    for (int i = tid; i < nbuck; i += 256)
        if (h[i]) atomicAdd(&ghist[i], h[i]);
}

// ---------------- bucket scan: gstart (exclusive) + gcursor init ----------------
__global__ __launch_bounds__(256) void gscan_k(const int* __restrict__ ghist,
                                               int* __restrict__ gstart, int* __restrict__ gcursor,
                                               int nbuck, int E) {
    __shared__ int wsum[256];
    int tid = threadIdx.x;
    int idx4 = tid * 4;
    int c[4];
    int mysum = 0;
#pragma unroll
    for (int j = 0; j < 4; ++j) {
        c[j] = (idx4 + j < nbuck) ? ghist[idx4 + j] : 0;
        mysum += c[j];
    }
    wsum[tid] = mysum;
    __syncthreads();
    for (int off = 1; off < 256; off <<= 1) {
        int add = (tid >= off) ? wsum[tid - off] : 0;
        __syncthreads();
        wsum[tid] += add;
        __syncthreads();
    }
    int run = wsum[tid] - mysum;
#pragma unroll
    for (int j = 0; j < 4; ++j) {
        if (idx4 + j < nbuck) { gstart[idx4 + j] = run; gcursor[idx4 + j] = run; }
        run += c[j];
    }
    if (tid == 255) gstart[nbuck] = E;
}

// ---------------- binA: LDS counting-sort chunk by bucket, grouped global write ----------------
// staged record: [55:49]=dstlow(7) [48:32]=src(17) [31:0]=w f32 bits
__global__ __launch_bounds__(256) void binA_k(const int* __restrict__ ei, const float* __restrict__ ew,
                                              int* __restrict__ gcursor,
                                              unsigned long long* __restrict__ stage, int E, int nbuck) {
    __shared__ unsigned long long sstage[4096];
    __shared__ int smeta[4096];
    __shared__ int cnt[NBUCK_MAX];
    __shared__ int lbase[NBUCK_MAX];
    __shared__ int gbase[NBUCK_MAX];
    __shared__ int cur[NBUCK_MAX];
    __shared__ int wsum[256];
    int tid = threadIdx.x;
    int e0 = blockIdx.x * 4096;
    int ecount = min(4096, E - e0);
    for (int i = tid; i < nbuck; i += 256) { cnt[i] = 0; cur[i] = 0; }
    __syncthreads();
    // local histogram
    for (int i = tid; i < ecount; i += 256)
        atomicAdd(&cnt[ei[E + e0 + i] >> 7], 1);
    __syncthreads();
    // exclusive scan of cnt -> lbase (4 entries/thread)
    int idx4 = tid * 4;
    int c[4];
    int mysum = 0;
#pragma unroll
    for (int j = 0; j < 4; ++j) {
        c[j] = (idx4 + j < nbuck) ? cnt[idx4 + j] : 0;
        mysum += c[j];
    }
    wsum[tid] = mysum;
    __syncthreads();
    for (int off = 1; off < 256; off <<= 1) {
        int add = (tid >= off) ? wsum[tid - off] : 0;
        __syncthreads();
        wsum[tid] += add;
        __syncthreads();
    }
    int run = wsum[tid] - mysum;
#pragma unroll
    for (int j = 0; j < 4; ++j) {
        if (idx4 + j < nbuck) lbase[idx4 + j] = run;
        run += c[j];
    }
    __syncthreads();
    // reserve global ranges (one atomic per non-empty bucket per block)
    for (int b = tid; b < nbuck; b += 256)
        gbase[b] = cnt[b] ? atomicAdd(&gcursor[b], cnt[b]) : 0;
    __syncthreads();
    // place into LDS grouped by bucket; record global target
    for (int i = tid; i < ecount; i += 256) {
        int e = e0 + i;
        int s = ei[e];
        int d = ei[E + e];
        unsigned int wb = __float_as_uint(ew[e]);
        int b = d >> 7;
        int off = atomicAdd(&cur[b], 1);
        int pos = lbase[b] + off;
        sstage[pos] = ((unsigned long long)(d & 127) << 49)
                    | ((unsigned long long)(unsigned int)s << 32) | wb;
        smeta[pos] = gbase[b] + off;
    }
    __syncthreads();
    // grouped write-out: consecutive pos -> mostly-consecutive global addresses
    for (int i = tid; i < ecount; i += 256)
        stage[smeta[i]] = sstage[i];
}

// ---------------- binB: per-bucket counting sort -> final CSR epack + rowptr/deg ----------------
__global__ __launch_bounds__(256) void binB_k(const unsigned long long* __restrict__ stage,
                                              const int* __restrict__ gstart,
                                              unsigned long long* __restrict__ epack,
                                              int* __restrict__ rowptr, int* __restrict__ deg, int N) {
    __shared__ unsigned long long lout[2048];
    __shared__ int cnt[128], exc[128], cur[128];
    int b = blockIdx.x;
    int tid = threadIdx.x;
    int base = gstart[b];
    int nb = gstart[b + 1] - base;
    if (tid < 128) { cnt[tid] = 0; cur[tid] = 0; }
    __syncthreads();
    for (int i = tid; i < nb; i += 256)
        atomicAdd(&cnt[(int)((stage[base + i] >> 49) & 127)], 1);
    __syncthreads();
    if (tid < 128) exc[tid] = cnt[tid];
    __syncthreads();
    for (int off = 1; off < 128; off <<= 1) {
        int add = (tid >= off && tid < 128) ? exc[tid - off] : 0;
        __syncthreads();
        if (tid < 128) exc[tid] += add;
        __syncthreads();
    }
    int node0 = b * 128;
    if (tid < 128) {
        exc[tid] -= cnt[tid];  // exclusive
        int node = node0 + tid;
        if (node < N) { deg[node] = cnt[tid]; rowptr[node] = base + exc[tid]; }
    }
    __syncthreads();
    for (int i = tid; i < nb; i += 256) {
        unsigned long long v = stage[base + i];
        int dl = (int)((v >> 49) & 127);
        unsigned int src = (unsigned int)((v >> 32) & 0x1FFFF);
        unsigned int wb = (unsigned int)v;
        int pos = exc[dl] + atomicAdd(&cur[dl], 1);
        unsigned long long outv = ((unsigned long long)wb << 32) | src;
        if (pos < 2048) lout[pos] = outv;
        else epack[base + pos] = outv;   // statistically unreachable overflow path
    }
    __syncthreads();
    int lim = min(nb, 2048);
    for (int i = tid; i < lim; i += 256)
        epack[base + i] = lout[i];
}

// ---------------- agg1: outb[n,:] = bf16(relu(sum_j w_j * bf2f(hb[src_j,:]))) ----------------
__global__ __launch_bounds__(256) void agg1_k(const unsigned short* __restrict__ hb,
                                              const int* __restrict__ rowptr, const int* __restrict__ deg,
                                              const int2* __restrict__ epack,
                                              unsigned short* __restrict__ outb, int N) {
    int node = blockIdx.x * 4 + (threadIdx.x >> 6);
    if (node >= N) return;
    int lane = threadIdx.x & 63;
    int start = rowptr[node];
    int cnt = deg[node];
    float acc0 = 0.f, acc1 = 0.f, acc2 = 0.f, acc3 = 0.f;
    int j = 0;
    for (; j + 3 < cnt; j += 4) {
        int2 p0 = epack[start + j];
        int2 p1 = epack[start + j + 1];
        int2 p2 = epack[start + j + 2];
        int2 p3 = epack[start + j + 3];
        acc0 = fmaf(__int_as_float(p0.y), bf2f(hb[(size_t)p0.x * H_DIM + lane]), acc0);
        acc1 = fmaf(__int_as_float(p1.y), bf2f(hb[(size_t)p1.x * H_DIM + lane]), acc1);
        acc2 = fmaf(__int_as_float(p2.y), bf2f(hb[(size_t)p2.x * H_DIM + lane]), acc2);
        acc3 = fmaf(__int_as_float(p3.y), bf2f(hb[(size_t)p3.x * H_DIM + lane]), acc3);
    }
    for (; j < cnt; ++j) {
        int2 p0 = epack[start + j];
        acc0 = fmaf(__int_as_float(p0.y), bf2f(hb[(size_t)p0.x * H_DIM + lane]), acc0);
    }
    float total = (acc0 + acc1) + (acc2 + acc3);
    outb[(size_t)node * H_DIM + lane] = f2bf(fmaxf(total, 0.f));
}

// ---------------- agg2 + fused projection ----------------
__global__ __launch_bounds__(256) void agg2p_k(const unsigned short* __restrict__ z2b,
                                               const int* __restrict__ rowptr, const int* __restrict__ deg,
                                               const int2* __restrict__ epack,
                                               const float* __restrict__ Wlin,  // [2,128]
                                               float4* __restrict__ u, int N) {
    int node = blockIdx.x * 4 + (threadIdx.x >> 6);
    if (node >= N) return;
    int lane = threadIdx.x & 63;
    int start = rowptr[node];
    int cnt = deg[node];
    float acc0 = 0.f, acc1 = 0.f, acc2 = 0.f, acc3 = 0.f;
    int j = 0;
    for (; j + 3 < cnt; j += 4) {
        int2 p0 = epack[start + j];
        int2 p1 = epack[start + j + 1];
        int2 p2 = epack[start + j + 2];
        int2 p3 = epack[start + j + 3];
        acc0 = fmaf(__int_as_float(p0.y), bf2f(z2b[(size_t)p0.x * H_DIM + lane]), acc0);
        acc1 = fmaf(__int_as_float(p1.y), bf2f(z2b[(size_t)p1.x * H_DIM + lane]), acc1);
        acc2 = fmaf(__int_as_float(p2.y), bf2f(z2b[(size_t)p2.x * H_DIM + lane]), acc2);
        acc3 = fmaf(__int_as_float(p3.y), bf2f(z2b[(size_t)p3.x * H_DIM + lane]), acc3);
    }
    for (; j < cnt; ++j) {
        int2 p0 = epack[start + j];
        acc0 = fmaf(__int_as_float(p0.y), bf2f(z2b[(size_t)p0.x * H_DIM + lane]), acc0);
    }
    float zl = (acc0 + acc1) + (acc2 + acc3);
    float p0 = zl * Wlin[lane];
    float p1 = zl * Wlin[128 + lane];
    float p2 = zl * Wlin[64 + lane];
    float p3 = zl * Wlin[192 + lane];
#pragma unroll
    for (int m = 32; m > 0; m >>= 1) {
        p0 += __shfl_xor(p0, m);
        p1 += __shfl_xor(p1, m);
        p2 += __shfl_xor(p2, m);
        p3 += __shfl_xor(p3, m);
    }
    if (lane == 0) u[node] = make_float4(p0, p1, p2, p3);
}

// ---------------- pair decode ----------------
__global__ __launch_bounds__(256) void pair_k(const float4* __restrict__ u,
                                              const int* __restrict__ pos,  // [2,P] flat
                                              float2* __restrict__ out, int P) {
    int p = blockIdx.x * 256 + threadIdx.x;
    if (p >= P) return;
    int s = pos[p];
    int t = pos[P + p];
    float4 us = u[s];
    float4 ut = u[t];
    out[p] = make_float2(us.x + ut.z, us.y + ut.w);
}

extern "C" void kernel_launch(void* const* d_in, const int* in_sizes, int n_in,
                              void* d_out, int out_size, void* d_ws, size_t ws_size,
                              hipStream_t stream) {
    const float* x    = (const float*)d_in[0];
    const int*   ei   = (const int*)d_in[1];    // [2,E]
    const float* ew   = (const float*)d_in[2];  // [E]
    const int*   pos  = (const int*)d_in[3];    // [2,P]
    const float* W1   = (const float*)d_in[4];  // [128,64]
    const float* W2   = (const float*)d_in[5];  // [64,64]
    const float* Wlin = (const float*)d_in[6];  // [2,128]
    float* out = (float*)d_out;

    const int N = in_sizes[0] / F_IN;      // 100000
    const int E = in_sizes[2];             // 1000000
    const int P = in_sizes[3] / 2;         // 500000
    const int nbuck = (N + 127) / 128;     // 782

    // workspace layout (bytes)
    char* ws = (char*)d_ws;
    const size_t rowBF = (size_t)N * H_DIM * sizeof(unsigned short);  // 12.8 MB
    unsigned short* hb   = (unsigned short*)ws;                // gemm1 out (bf16)
    unsigned short* a1b  = (unsigned short*)(ws + rowBF);      // relu(agg1) (bf16)
    unsigned short* z2b  = (unsigned short*)(ws + 2 * rowBF);  // gemm2 out (bf16)
    float4*         u    = (float4*)(ws + 3 * rowBF);          // N float4
    unsigned long long* epack = (unsigned long long*)(ws + 3 * rowBF + (size_t)N * 16);
    unsigned long long* stage = epack + E;
    int* ghist   = (int*)(stage + E);
    int* gstart  = ghist + NBUCK_MAX;          // nbuck+1
    int* gcursor = gstart + NBUCK_MAX + 1;
    int* rowptr  = gcursor + NBUCK_MAX;
    int* deg     = rowptr + N;
    // 16B-aligned prepacked weight fragments
    size_t wf_off = (((size_t)((char*)(deg + N) - ws)) + 15) & ~(size_t)15;
    unsigned short* wf1 = (unsigned short*)(ws + wf_off);      // 16 KB
    unsigned short* wf2 = wf1 + 4 * 4 * 64 * 8;                // 8 KB

    // weight prepack (tiny)
    prepack_k<<<4, 256, 0, stream>>>(W1, wf1, F_IN);
    prepack_k<<<2, 256, 0, stream>>>(W2, wf2, H_DIM);

    // conv1 matmul (x f32 -> bf16 in-register) -> hb
    mfma_gemm_k<F_IN, true><<<(N + 63) / 64, 256, 0, stream>>>(x, wf1, hb, N);

    // binning sort -> CSR (epack, rowptr, deg)
    hipMemsetAsync(ghist, 0, (size_t)nbuck * sizeof(int), stream);
    ghist_k<<<(E + 8191) / 8192, 256, 0, stream>>>(ei, ghist, E, nbuck);
    gscan_k<<<1, 256, 0, stream>>>(ghist, gstart, gcursor, nbuck, E);
    binA_k<<<(E + 4095) / 4096, 256, 0, stream>>>(ei, ew, gcursor, stage, E, nbuck);
    binB_k<<<nbuck, 256, 0, stream>>>(stage, gstart, epack, rowptr, deg, N);

    // agg1: hb -> a1b (bf16, relu fused)
    agg1_k<<<(N + 3) / 4, 256, 0, stream>>>(hb, rowptr, deg, (const int2*)epack, a1b, N);
    // conv2 matmul: a1b -> z2b
    mfma_gemm_k<H_DIM, false><<<(N + 63) / 64, 256, 0, stream>>>(a1b, wf2, z2b, N);
    // agg2 + fused projection: z2b -> u
    agg2p_k<<<(N + 3) / 4, 256, 0, stream>>>(z2b, rowptr, deg, (const int2*)epack, Wlin, u, N);
    // pair decode
    pair_k<<<(P + 255) / 256, 256, 0, stream>>>(u, pos, (float2*)out, P);
}

// Round 8
// 142.079 us; speedup vs baseline: 2.4651x; 1.3301x over previous
//
#include <hip/hip_runtime.h>

#define F_IN 128
#define H_DIM 64
#define NBUCK_MAX 1024   // buckets of 128 nodes; N <= 131072

typedef short s16x8 __attribute__((ext_vector_type(8)));
typedef float f32x4 __attribute__((ext_vector_type(4)));

union FragU {
    s16x8 s;
    uint4 q;
    unsigned short u[8];
};

__device__ __forceinline__ unsigned short f2bf(float f) {
    unsigned int b = __float_as_uint(f);
    b += 0x7fffu + ((b >> 16) & 1u);
    return (unsigned short)(b >> 16);
}
__device__ __forceinline__ float bf2f(unsigned short u) {
    return __uint_as_float((unsigned int)u << 16);
}

// ---------------- W prepack: W[K x 64] f32 -> B-fragments bf16 ----------------
__global__ __launch_bounds__(256) void prepack_k(const float* __restrict__ W,
                                                 unsigned short* __restrict__ wf, int K) {
    int KS = K / 32;
    int total = 4 * KS * 64;
    int tid = blockIdx.x * 256 + threadIdx.x;
    if (tid >= total) return;
    int lane = tid & 63;
    int grp = tid >> 6;
    int ks = grp % KS;
    int ct = grp / KS;
    int col = ct * 16 + (lane & 15);
    int kbase = ks * 32 + (lane >> 4) * 8;
    FragU f;
#pragma unroll
    for (int j = 0; j < 8; ++j) f.u[j] = f2bf(W[(kbase + j) * H_DIM + col]);
    reinterpret_cast<uint4*>(wf)[tid] = f.q;
}

// ---------------- MFMA GEMM1: hb = bf16(x @ W1) [N x 128]@[128 x 64] ----------------
__global__ __launch_bounds__(256) void gemm1_k(const float* __restrict__ x,
                                               const unsigned short* __restrict__ wf,
                                               unsigned short* __restrict__ outb, int N) {
    constexpr int KS = F_IN / 32;
    int wv = threadIdx.x >> 6;
    int lane = threadIdx.x & 63;
    int rb = blockIdx.x * 64 + wv * 16;
    int ra = rb + (lane & 15);
    if (ra > N - 1) ra = N - 1;
    int koct = lane >> 4;

    FragU af[KS];
    const float* ap = x + (size_t)ra * F_IN + koct * 8;
#pragma unroll
    for (int ks = 0; ks < KS; ++ks) {
        float4 v0 = *reinterpret_cast<const float4*>(ap + ks * 32);
        float4 v1 = *reinterpret_cast<const float4*>(ap + ks * 32 + 4);
        af[ks].u[0] = f2bf(v0.x); af[ks].u[1] = f2bf(v0.y);
        af[ks].u[2] = f2bf(v0.z); af[ks].u[3] = f2bf(v0.w);
        af[ks].u[4] = f2bf(v1.x); af[ks].u[5] = f2bf(v1.y);
        af[ks].u[6] = f2bf(v1.z); af[ks].u[7] = f2bf(v1.w);
    }

    const uint4* bq = reinterpret_cast<const uint4*>(wf);
    f32x4 acc[4];
#pragma unroll
    for (int ct = 0; ct < 4; ++ct) acc[ct] = (f32x4){0.f, 0.f, 0.f, 0.f};
#pragma unroll
    for (int ct = 0; ct < 4; ++ct) {
#pragma unroll
        for (int ks = 0; ks < KS; ++ks) {
            FragU b;
            b.q = bq[(ct * KS + ks) * 64 + lane];
            acc[ct] = __builtin_amdgcn_mfma_f32_16x16x32_bf16(af[ks].s, b.s, acc[ct], 0, 0, 0);
        }
    }

    int ro_base = rb + (lane >> 4) * 4;
    int col = lane & 15;
#pragma unroll
    for (int ct = 0; ct < 4; ++ct) {
#pragma unroll
        for (int j = 0; j < 4; ++j) {
            int ro = ro_base + j;
            if (ro < N) outb[(size_t)ro * H_DIM + ct * 16 + col] = f2bf(acc[ct][j]);
        }
    }
}

// ---------------- MFMA GEMM2 + fused proj: uz[row] = (z2row·A0, z2row·A1, z2row·B0, z2row·B1)
// z2 = a1b @ W2 stays in accumulators; never written to memory.
__global__ __launch_bounds__(256) void gemm2v_k(const unsigned short* __restrict__ a1b,
                                                const unsigned short* __restrict__ wf,
                                                const float* __restrict__ Wlin,  // [2,128]
                                                float4* __restrict__ uz, int N) {
    constexpr int KS = H_DIM / 32;
    int wv = threadIdx.x >> 6;
    int lane = threadIdx.x & 63;
    int rb = blockIdx.x * 64 + wv * 16;
    int ra = rb + (lane & 15);
    if (ra > N - 1) ra = N - 1;
    int koct = lane >> 4;

    FragU af[KS];
    const unsigned short* ap = a1b + (size_t)ra * H_DIM + koct * 8;
#pragma unroll
    for (int ks = 0; ks < KS; ++ks)
        af[ks].q = *reinterpret_cast<const uint4*>(ap + ks * 32);

    const uint4* bq = reinterpret_cast<const uint4*>(wf);
    f32x4 acc[4];
#pragma unroll
    for (int ct = 0; ct < 4; ++ct) acc[ct] = (f32x4){0.f, 0.f, 0.f, 0.f};
#pragma unroll
    for (int ct = 0; ct < 4; ++ct) {
#pragma unroll
        for (int ks = 0; ks < KS; ++ks) {
            FragU b;
            b.q = bq[(ct * KS + ks) * 64 + lane];
            acc[ct] = __builtin_amdgcn_mfma_f32_16x16x32_bf16(af[ks].s, b.s, acc[ct], 0, 0, 0);
        }
    }

    // epilogue: project rows. Lane holds cols (ct*16 + c) of rows ro_base..+3.
    int c = lane & 15;
    float w0[4], w1[4], w2[4], w3[4];
#pragma unroll
    for (int ct = 0; ct < 4; ++ct) {
        int col = ct * 16 + c;
        w0[ct] = Wlin[col];        // A0 (row0, src half)
        w1[ct] = Wlin[128 + col];  // A1 (row1, src half)
        w2[ct] = Wlin[64 + col];   // B0 (row0, dst half)
        w3[ct] = Wlin[192 + col];  // B1 (row1, dst half)
    }
    int ro_base = rb + (lane >> 4) * 4;
#pragma unroll
    for (int j = 0; j < 4; ++j) {
        float p0 = 0.f, p1 = 0.f, p2 = 0.f, p3 = 0.f;
#pragma unroll
        for (int ct = 0; ct < 4; ++ct) {
            float zv = acc[ct][j];
            p0 = fmaf(zv, w0[ct], p0);
            p1 = fmaf(zv, w1[ct], p1);
            p2 = fmaf(zv, w2[ct], p2);
            p3 = fmaf(zv, w3[ct], p3);
        }
#pragma unroll
        for (int m = 1; m < 16; m <<= 1) {
            p0 += __shfl_xor(p0, m);
            p1 += __shfl_xor(p1, m);
            p2 += __shfl_xor(p2, m);
            p3 += __shfl_xor(p3, m);
        }
        int ro = ro_base + j;
        if (c == 0 && ro < N) uz[ro] = make_float4(p0, p1, p2, p3);
    }
}

// ---------------- binning sort: global bucket histogram ----------------
__global__ __launch_bounds__(256) void ghist_k(const int* __restrict__ ei,
                                               int* __restrict__ ghist, int E, int nbuck) {
    __shared__ int h[NBUCK_MAX];
    int tid = threadIdx.x;
    for (int i = tid; i < nbuck; i += 256) h[i] = 0;
    __syncthreads();
    int e0 = blockIdx.x * 8192;
    int ecount = min(8192, E - e0);
    for (int i = tid; i < ecount; i += 256)
        atomicAdd(&h[ei[E + e0 + i] >> 7], 1);
    __syncthreads();
    for (int i = tid; i < nbuck; i += 256)
        if (h[i]) atomicAdd(&ghist[i], h[i]);
}

// ---------------- bucket scan ----------------
__global__ __launch_bounds__(256) void gscan_k(const int* __restrict__ ghist,
                                               int* __restrict__ gstart, int* __restrict__ gcursor,
                                               int nbuck, int E) {
    __shared__ int wsum[256];
    int tid = threadIdx.x;
    int idx4 = tid * 4;
    int c[4];
    int mysum = 0;
#pragma unroll
    for (int j = 0; j < 4; ++j) {
        c[j] = (idx4 + j < nbuck) ? ghist[idx4 + j] : 0;
        mysum += c[j];
    }
    wsum[tid] = mysum;
    __syncthreads();
    for (int off = 1; off < 256; off <<= 1) {
        int add = (tid >= off) ? wsum[tid - off] : 0;
        __syncthreads();
        wsum[tid] += add;
        __syncthreads();
    }
    int run = wsum[tid] - mysum;
#pragma unroll
    for (int j = 0; j < 4; ++j) {
        if (idx4 + j < nbuck) { gstart[idx4 + j] = run; gcursor[idx4 + j] = run; }
        run += c[j];
    }
    if (tid == 255) gstart[nbuck] = E;
}

// ---------------- binA: LDS counting-sort chunk by bucket, grouped global write ----------------
__global__ __launch_bounds__(256) void binA_k(const int* __restrict__ ei, const float* __restrict__ ew,
                                              int* __restrict__ gcursor,
                                              unsigned long long* __restrict__ stage, int E, int nbuck) {
    __shared__ unsigned long long sstage[4096];
    __shared__ int smeta[4096];
    __shared__ int cnt[NBUCK_MAX];
    __shared__ int lbase[NBUCK_MAX];
    __shared__ int gbase[NBUCK_MAX];
    __shared__ int cur[NBUCK_MAX];
    __shared__ int wsum[256];
    int tid = threadIdx.x;
    int e0 = blockIdx.x * 4096;
    int ecount = min(4096, E - e0);
    for (int i = tid; i < nbuck; i += 256) { cnt[i] = 0; cur[i] = 0; }
    __syncthreads();
    for (int i = tid; i < ecount; i += 256)
        atomicAdd(&cnt[ei[E + e0 + i] >> 7], 1);
    __syncthreads();
    int idx4 = tid * 4;
    int c[4];
    int mysum = 0;
#pragma unroll
    for (int j = 0; j < 4; ++j) {
        c[j] = (idx4 + j < nbuck) ? cnt[idx4 + j] : 0;
        mysum += c[j];
    }
    wsum[tid] = mysum;
    __syncthreads();
    for (int off = 1; off < 256; off <<= 1) {
        int add = (tid >= off) ? wsum[tid - off] : 0;
        __syncthreads();
        wsum[tid] += add;
        __syncthreads();
    }
    int run = wsum[tid] - mysum;
#pragma unroll
    for (int j = 0; j < 4; ++j) {
        if (idx4 + j < nbuck) lbase[idx4 + j] = run;
        run += c[j];
    }
    __syncthreads();
    for (int b = tid; b < nbuck; b += 256)
        gbase[b] = cnt[b] ? atomicAdd(&gcursor[b], cnt[b]) : 0;
    __syncthreads();
    for (int i = tid; i < ecount; i += 256) {
        int e = e0 + i;
        int s = ei[e];
        int d = ei[E + e];
        unsigned int wb = __float_as_uint(ew[e]);
        int b = d >> 7;
        int off = atomicAdd(&cur[b], 1);
        int pos = lbase[b] + off;
        sstage[pos] = ((unsigned long long)(d & 127) << 49)
                    | ((unsigned long long)(unsigned int)s << 32) | wb;
        smeta[pos] = gbase[b] + off;
    }
    __syncthreads();
    for (int i = tid; i < ecount; i += 256)
        stage[smeta[i]] = sstage[i];
}

// ---------------- binB: per-bucket counting sort -> final CSR epack + rowptr/deg ----------------
// epack record: low32 = src, high32 = w bits
__global__ __launch_bounds__(256) void binB_k(const unsigned long long* __restrict__ stage,
                                              const int* __restrict__ gstart,
                                              unsigned long long* __restrict__ epack,
                                              int* __restrict__ rowptr, int* __restrict__ deg, int N) {
    __shared__ unsigned long long lout[2048];
    __shared__ int cnt[128], exc[128], cur[128];
    int b = blockIdx.x;
    int tid = threadIdx.x;
    int base = gstart[b];
    int nb = gstart[b + 1] - base;
    if (tid < 128) { cnt[tid] = 0; cur[tid] = 0; }
    __syncthreads();
    for (int i = tid; i < nb; i += 256)
        atomicAdd(&cnt[(int)((stage[base + i] >> 49) & 127)], 1);
    __syncthreads();
    if (tid < 128) exc[tid] = cnt[tid];
    __syncthreads();
    for (int off = 1; off < 128; off <<= 1) {
        int add = (tid >= off && tid < 128) ? exc[tid - off] : 0;
        __syncthreads();
        if (tid < 128) exc[tid] += add;
        __syncthreads();
    }
    int node0 = b * 128;
    if (tid < 128) {
        exc[tid] -= cnt[tid];  // exclusive
        int node = node0 + tid;
        if (node < N) { deg[node] = cnt[tid]; rowptr[node] = base + exc[tid]; }
    }
    __syncthreads();
    for (int i = tid; i < nb; i += 256) {
        unsigned long long v = stage[base + i];
        int dl = (int)((v >> 49) & 127);
        unsigned int src = (unsigned int)((v >> 32) & 0x1FFFF);
        unsigned int wb = (unsigned int)v;
        int pos = exc[dl] + atomicAdd(&cur[dl], 1);
        unsigned long long outv = ((unsigned long long)wb << 32) | src;
        if (pos < 2048) lout[pos] = outv;
        else epack[base + pos] = outv;
    }
    __syncthreads();
    int lim = min(nb, 2048);
    for (int i = tid; i < lim; i += 256)
        epack[base + i] = lout[i];
}

// ---------------- agg1 (row-split): outb[n,:] = bf16(relu(sum_j w_j*hb[src_j,:])) ----------------
// Wave per node; lane = (edge-slot 0..3)<<4 | (dim-group 0..15). Each lane
// gathers uint2 (4 bf16); epack load amortized over 16 lanes; 8 shfl reduce.
__global__ __launch_bounds__(256) void agg1_k(const unsigned short* __restrict__ hb,
                                              const int* __restrict__ rowptr, const int* __restrict__ deg,
                                              const unsigned long long* __restrict__ epack,
                                              unsigned short* __restrict__ outb, int N) {
    int node = blockIdx.x * 4 + (threadIdx.x >> 6);
    if (node >= N) return;
    int lane = threadIdx.x & 63;
    int slot = lane >> 4;
    int dimg = lane & 15;
    int start = rowptr[node];
    int cnt = deg[node];
    float a0 = 0.f, a1 = 0.f, a2 = 0.f, a3 = 0.f;
    for (int j = slot; j < cnt; j += 4) {
        unsigned long long p = epack[start + j];
        float w = __uint_as_float((unsigned int)(p >> 32));
        unsigned int src = (unsigned int)p;
        uint2 v = *reinterpret_cast<const uint2*>(hb + (size_t)src * H_DIM + dimg * 4);
        a0 = fmaf(w, __uint_as_float(v.x << 16), a0);
        a1 = fmaf(w, __uint_as_float(v.x & 0xffff0000u), a1);
        a2 = fmaf(w, __uint_as_float(v.y << 16), a2);
        a3 = fmaf(w, __uint_as_float(v.y & 0xffff0000u), a3);
    }
    a0 += __shfl_xor(a0, 16); a0 += __shfl_xor(a0, 32);
    a1 += __shfl_xor(a1, 16); a1 += __shfl_xor(a1, 32);
    a2 += __shfl_xor(a2, 16); a2 += __shfl_xor(a2, 32);
    a3 += __shfl_xor(a3, 16); a3 += __shfl_xor(a3, 32);
    if (slot == 0) {
        uint2 o;
        o.x = (unsigned int)f2bf(fmaxf(a0, 0.f)) | ((unsigned int)f2bf(fmaxf(a1, 0.f)) << 16);
        o.y = (unsigned int)f2bf(fmaxf(a2, 0.f)) | ((unsigned int)f2bf(fmaxf(a3, 0.f)) << 16);
        *reinterpret_cast<uint2*>(outb + (size_t)node * H_DIM + dimg * 4) = o;
    }
}

// ---------------- aggv: u[n] = sum_j w_j * uz[src_j]  (thread per node, float4) ----------------
__global__ __launch_bounds__(256) void aggv_k(const float4* __restrict__ uz,
                                              const int* __restrict__ rowptr, const int* __restrict__ deg,
                                              const unsigned long long* __restrict__ epack,
                                              float4* __restrict__ u, int N) {
    int node = blockIdx.x * 256 + threadIdx.x;
    if (node >= N) return;
    int start = rowptr[node];
    int cnt = deg[node];
    float4 acc = make_float4(0.f, 0.f, 0.f, 0.f);
    int j = 0;
    for (; j + 3 < cnt; j += 4) {
#pragma unroll
        for (int q = 0; q < 4; ++q) {
            unsigned long long p = epack[start + j + q];
            float w = __uint_as_float((unsigned int)(p >> 32));
            float4 v = uz[(unsigned int)p];
            acc.x = fmaf(w, v.x, acc.x);
            acc.y = fmaf(w, v.y, acc.y);
            acc.z = fmaf(w, v.z, acc.z);
            acc.w = fmaf(w, v.w, acc.w);
        }
    }
    for (; j < cnt; ++j) {
        unsigned long long p = epack[start + j];
        float w = __uint_as_float((unsigned int)(p >> 32));
        float4 v = uz[(unsigned int)p];
        acc.x = fmaf(w, v.x, acc.x);
        acc.y = fmaf(w, v.y, acc.y);
        acc.z = fmaf(w, v.z, acc.z);
        acc.w = fmaf(w, v.w, acc.w);
    }
    u[node] = acc;
}

// ---------------- pair decode ----------------
__global__ __launch_bounds__(256) void pair_k(const float4* __restrict__ u,
                                              const int* __restrict__ pos,  // [2,P] flat
                                              float2* __restrict__ out, int P) {
    int p = blockIdx.x * 256 + threadIdx.x;
    if (p >= P) return;
    int s = pos[p];
    int t = pos[P + p];
    float4 us = u[s];
    float4 ut = u[t];
    out[p] = make_float2(us.x + ut.z, us.y + ut.w);
}

extern "C" void kernel_launch(void* const* d_in, const int* in_sizes, int n_in,
                              void* d_out, int out_size, void* d_ws, size_t ws_size,
                              hipStream_t stream) {
    const float* x    = (const float*)d_in[0];
    const int*   ei   = (const int*)d_in[1];    // [2,E]
    const float* ew   = (const float*)d_in[2];  // [E]
    const int*   pos  = (const int*)d_in[3];    // [2,P]
    const float* W1   = (const float*)d_in[4];  // [128,64]
    const float* W2   = (const float*)d_in[5];  // [64,64]
    const float* Wlin = (const float*)d_in[6];  // [2,128]
    float* out = (float*)d_out;

    const int N = in_sizes[0] / F_IN;      // 100000
    const int E = in_sizes[2];             // 1000000
    const int P = in_sizes[3] / 2;         // 500000
    const int nbuck = (N + 127) / 128;     // 782

    // workspace layout (bytes)
    char* ws = (char*)d_ws;
    const size_t rowBF = (size_t)N * H_DIM * sizeof(unsigned short);  // 12.8 MB
    unsigned short* hb   = (unsigned short*)ws;                // gemm1 out (bf16)
    unsigned short* a1b  = (unsigned short*)(ws + rowBF);      // relu(agg1) (bf16)
    float4*         uz   = (float4*)(ws + 2 * rowBF);          // N float4 (proj of z2 rows)
    float4*         u    = uz + N;                             // N float4
    unsigned long long* epack = (unsigned long long*)((char*)(u + N));
    unsigned long long* stage = epack + E;
    int* ghist   = (int*)(stage + E);
    int* gstart  = ghist + NBUCK_MAX;          // nbuck+1
    int* gcursor = gstart + NBUCK_MAX + 1;
    int* rowptr  = gcursor + NBUCK_MAX;
    int* deg     = rowptr + N;
    size_t wf_off = (((size_t)((char*)(deg + N) - ws)) + 15) & ~(size_t)15;
    unsigned short* wf1 = (unsigned short*)(ws + wf_off);      // 16 KB
    unsigned short* wf2 = wf1 + 4 * 4 * 64 * 8;                // 8 KB

    // weight prepack (tiny)
    prepack_k<<<4, 256, 0, stream>>>(W1, wf1, F_IN);
    prepack_k<<<2, 256, 0, stream>>>(W2, wf2, H_DIM);

    // conv1 matmul (x f32 -> bf16 in-register) -> hb
    gemm1_k<<<(N + 63) / 64, 256, 0, stream>>>(x, wf1, hb, N);

    // binning sort -> CSR (epack, rowptr, deg)
    hipMemsetAsync(ghist, 0, (size_t)nbuck * sizeof(int), stream);
    ghist_k<<<(E + 8191) / 8192, 256, 0, stream>>>(ei, ghist, E, nbuck);
    gscan_k<<<1, 256, 0, stream>>>(ghist, gstart, gcursor, nbuck, E);
    binA_k<<<(E + 4095) / 4096, 256, 0, stream>>>(ei, ew, gcursor, stage, E, nbuck);
    binB_k<<<nbuck, 256, 0, stream>>>(stage, gstart, epack, rowptr, deg, N);

    // agg1: hb -> a1b (bf16, relu fused)
    agg1_k<<<(N + 3) / 4, 256, 0, stream>>>(hb, rowptr, deg, epack, a1b, N);
    // conv2 matmul + fused projection: a1b -> uz (z2 never materialized)
    gemm2v_k<<<(N + 63) / 64, 256, 0, stream>>>(a1b, wf2, Wlin, uz, N);
    // agg2 on projected vectors: uz -> u
    aggv_k<<<(N + 255) / 256, 256, 0, stream>>>(uz, rowptr, deg, epack, u, N);
    // pair decode
    pair_k<<<(P + 255) / 256, 256, 0, stream>>>(u, pos, (float2*)out, P);
}

// Round 10
// 135.854 us; speedup vs baseline: 2.5781x; 1.0458x over previous
//
#include <hip/hip_runtime.h>

#define F_IN 128
#define H_DIM 64
#define NBUCK_MAX 1024   // buckets of 128 nodes; N <= 131072

typedef short s16x8 __attribute__((ext_vector_type(8)));
typedef float f32x4 __attribute__((ext_vector_type(4)));

union FragU {
    s16x8 s;
    uint4 q;
    unsigned short u[8];
};

__device__ __forceinline__ unsigned short f2bf(float f) {
    unsigned int b = __float_as_uint(f);
    b += 0x7fffu + ((b >> 16) & 1u);
    return (unsigned short)(b >> 16);
}
__device__ __forceinline__ float bf2f(unsigned short u) {
    return __uint_as_float((unsigned int)u << 16);
}

// ---------------- W prepack: W[K x 64] f32 -> B-fragments bf16 ----------------
__global__ __launch_bounds__(256) void prepack_k(const float* __restrict__ W,
                                                 unsigned short* __restrict__ wf, int K) {
    int KS = K / 32;
    int total = 4 * KS * 64;
    int tid = blockIdx.x * 256 + threadIdx.x;
    if (tid >= total) return;
    int lane = tid & 63;
    int grp = tid >> 6;
    int ks = grp % KS;
    int ct = grp / KS;
    int col = ct * 16 + (lane & 15);
    int kbase = ks * 32 + (lane >> 4) * 8;
    FragU f;
#pragma unroll
    for (int j = 0; j < 8; ++j) f.u[j] = f2bf(W[(kbase + j) * H_DIM + col]);
    reinterpret_cast<uint4*>(wf)[tid] = f.q;
}

// ---------------- MFMA GEMM1: hb = bf16(x @ W1) [N x 128]@[128 x 64] ----------------
__global__ __launch_bounds__(256) void gemm1_k(const float* __restrict__ x,
                                               const unsigned short* __restrict__ wf,
                                               unsigned short* __restrict__ outb, int N) {
    constexpr int KS = F_IN / 32;
    int wv = threadIdx.x >> 6;
    int lane = threadIdx.x & 63;
    int rb = blockIdx.x * 64 + wv * 16;
    int ra = rb + (lane & 15);
    if (ra > N - 1) ra = N - 1;
    int koct = lane >> 4;

    FragU af[KS];
    const float* ap = x + (size_t)ra * F_IN + koct * 8;
#pragma unroll
    for (int ks = 0; ks < KS; ++ks) {
        float4 v0 = *reinterpret_cast<const float4*>(ap + ks * 32);
        float4 v1 = *reinterpret_cast<const float4*>(ap + ks * 32 + 4);
        af[ks].u[0] = f2bf(v0.x); af[ks].u[1] = f2bf(v0.y);
        af[ks].u[2] = f2bf(v0.z); af[ks].u[3] = f2bf(v0.w);
        af[ks].u[4] = f2bf(v1.x); af[ks].u[5] = f2bf(v1.y);
        af[ks].u[6] = f2bf(v1.z); af[ks].u[7] = f2bf(v1.w);
    }

    const uint4* bq = reinterpret_cast<const uint4*>(wf);
    f32x4 acc[4];
#pragma unroll
    for (int ct = 0; ct < 4; ++ct) acc[ct] = (f32x4){0.f, 0.f, 0.f, 0.f};
#pragma unroll
    for (int ct = 0; ct < 4; ++ct) {
#pragma unroll
        for (int ks = 0; ks < KS; ++ks) {
            FragU b;
            b.q = bq[(ct * KS + ks) * 64 + lane];
            acc[ct] = __builtin_amdgcn_mfma_f32_16x16x32_bf16(af[ks].s, b.s, acc[ct], 0, 0, 0);
        }
    }

    int ro_base = rb + (lane >> 4) * 4;
    int col = lane & 15;
#pragma unroll
    for (int ct = 0; ct < 4; ++ct) {
#pragma unroll
        for (int j = 0; j < 4; ++j) {
            int ro = ro_base + j;
            if (ro < N) outb[(size_t)ro * H_DIM + ct * 16 + col] = f2bf(acc[ct][j]);
        }
    }
}

// ---------------- MFMA GEMM2 + fused proj: uz[row] = (z2row·A0, z2row·A1, z2row·B0, z2row·B1)
__global__ __launch_bounds__(256) void gemm2v_k(const unsigned short* __restrict__ a1b,
                                                const unsigned short* __restrict__ wf,
                                                const float* __restrict__ Wlin,  // [2,128]
                                                float4* __restrict__ uz, int N) {
    constexpr int KS = H_DIM / 32;
    int wv = threadIdx.x >> 6;
    int lane = threadIdx.x & 63;
    int rb = blockIdx.x * 64 + wv * 16;
    int ra = rb + (lane & 15);
    if (ra > N - 1) ra = N - 1;
    int koct = lane >> 4;

    FragU af[KS];
    const unsigned short* ap = a1b + (size_t)ra * H_DIM + koct * 8;
#pragma unroll
    for (int ks = 0; ks < KS; ++ks)
        af[ks].q = *reinterpret_cast<const uint4*>(ap + ks * 32);

    const uint4* bq = reinterpret_cast<const uint4*>(wf);
    f32x4 acc[4];
#pragma unroll
    for (int ct = 0; ct < 4; ++ct) acc[ct] = (f32x4){0.f, 0.f, 0.f, 0.f};
#pragma unroll
    for (int ct = 0; ct < 4; ++ct) {
#pragma unroll
        for (int ks = 0; ks < KS; ++ks) {
            FragU b;
            b.q = bq[(ct * KS + ks) * 64 + lane];
            acc[ct] = __builtin_amdgcn_mfma_f32_16x16x32_bf16(af[ks].s, b.s, acc[ct], 0, 0, 0);
        }
    }

    int c = lane & 15;
    float w0[4], w1[4], w2[4], w3[4];
#pragma unroll
    for (int ct = 0; ct < 4; ++ct) {
        int col = ct * 16 + c;
        w0[ct] = Wlin[col];        // A0
        w1[ct] = Wlin[128 + col];  // A1
        w2[ct] = Wlin[64 + col];   // B0
        w3[ct] = Wlin[192 + col];  // B1
    }
    int ro_base = rb + (lane >> 4) * 4;
#pragma unroll
    for (int j = 0; j < 4; ++j) {
        float p0 = 0.f, p1 = 0.f, p2 = 0.f, p3 = 0.f;
#pragma unroll
        for (int ct = 0; ct < 4; ++ct) {
            float zv = acc[ct][j];
            p0 = fmaf(zv, w0[ct], p0);
            p1 = fmaf(zv, w1[ct], p1);
            p2 = fmaf(zv, w2[ct], p2);
            p3 = fmaf(zv, w3[ct], p3);
        }
#pragma unroll
        for (int m = 1; m < 16; m <<= 1) {
            p0 += __shfl_xor(p0, m);
            p1 += __shfl_xor(p1, m);
            p2 += __shfl_xor(p2, m);
            p3 += __shfl_xor(p3, m);
        }
        int ro = ro_base + j;
        if (c == 0 && ro < N) uz[ro] = make_float4(p0, p1, p2, p3);
    }
}

// ---------------- binning sort: global bucket histogram ----------------
__global__ __launch_bounds__(256) void ghist_k(const int* __restrict__ ei,
                                               int* __restrict__ ghist, int E, int nbuck) {
    __shared__ int h[NBUCK_MAX];
    int tid = threadIdx.x;
    for (int i = tid; i < nbuck; i += 256) h[i] = 0;
    __syncthreads();
    int e0 = blockIdx.x * 8192;
    int ecount = min(8192, E - e0);
    for (int i = tid; i < ecount; i += 256)
        atomicAdd(&h[ei[E + e0 + i] >> 7], 1);
    __syncthreads();
    for (int i = tid; i < nbuck; i += 256)
        if (h[i]) atomicAdd(&ghist[i], h[i]);
}

// ---------------- bucket scan ----------------
__global__ __launch_bounds__(256) void gscan_k(const int* __restrict__ ghist,
                                               int* __restrict__ gstart, int* __restrict__ gcursor,
                                               int nbuck, int E) {
    __shared__ int wsum[256];
    int tid = threadIdx.x;
    int idx4 = tid * 4;
    int c[4];
    int mysum = 0;
#pragma unroll
    for (int j = 0; j < 4; ++j) {
        c[j] = (idx4 + j < nbuck) ? ghist[idx4 + j] : 0;
        mysum += c[j];
    }
    wsum[tid] = mysum;
    __syncthreads();
    for (int off = 1; off < 256; off <<= 1) {
        int add = (tid >= off) ? wsum[tid - off] : 0;
        __syncthreads();
        wsum[tid] += add;
        __syncthreads();
    }
    int run = wsum[tid] - mysum;
#pragma unroll
    for (int j = 0; j < 4; ++j) {
        if (idx4 + j < nbuck) { gstart[idx4 + j] = run; gcursor[idx4 + j] = run; }
        run += c[j];
    }
    if (tid == 255) gstart[nbuck] = E;
}

// ---------------- binA: LDS counting-sort chunk by bucket, grouped global write ----------------
__global__ __launch_bounds__(256) void binA_k(const int* __restrict__ ei, const float* __restrict__ ew,
                                              int* __restrict__ gcursor,
                                              unsigned long long* __restrict__ stage, int E, int nbuck) {
    __shared__ unsigned long long sstage[4096];
    __shared__ int smeta[4096];
    __shared__ int cnt[NBUCK_MAX];
    __shared__ int lbase[NBUCK_MAX];
    __shared__ int gbase[NBUCK_MAX];
    __shared__ int cur[NBUCK_MAX];
    __shared__ int wsum[256];
    int tid = threadIdx.x;
    int e0 = blockIdx.x * 4096;
    int ecount = min(4096, E - e0);
    for (int i = tid; i < nbuck; i += 256) { cnt[i] = 0; cur[i] = 0; }
    __syncthreads();
    for (int i = tid; i < ecount; i += 256)
        atomicAdd(&cnt[ei[E + e0 + i] >> 7], 1);
    __syncthreads();
    int idx4 = tid * 4;
    int c[4];
    int mysum = 0;
#pragma unroll
    for (int j = 0; j < 4; ++j) {
        c[j] = (idx4 + j < nbuck) ? cnt[idx4 + j] : 0;
        mysum += c[j];
    }
    wsum[tid] = mysum;
    __syncthreads();
    for (int off = 1; off < 256; off <<= 1) {
        int add = (tid >= off) ? wsum[tid - off] : 0;
        __syncthreads();
        wsum[tid] += add;
        __syncthreads();
    }
    int run = wsum[tid] - mysum;
#pragma unroll
    for (int j = 0; j < 4; ++j) {
        if (idx4 + j < nbuck) lbase[idx4 + j] = run;
        run += c[j];
    }
    __syncthreads();
    for (int b = tid; b < nbuck; b += 256)
        gbase[b] = cnt[b] ? atomicAdd(&gcursor[b], cnt[b]) : 0;
    __syncthreads();
    for (int i = tid; i < ecount; i += 256) {
        int e = e0 + i;
        int s = ei[e];
        int d = ei[E + e];
        unsigned int wb = __float_as_uint(ew[e]);
        int b = d >> 7;
        int off = atomicAdd(&cur[b], 1);
        int pos = lbase[b] + off;
        sstage[pos] = ((unsigned long long)(d & 127) << 49)
                    | ((unsigned long long)(unsigned int)s << 32) | wb;
        smeta[pos] = gbase[b] + off;
    }
    __syncthreads();
    for (int i = tid; i < ecount; i += 256)
        stage[smeta[i]] = sstage[i];
}

// ---------------- binB: per-bucket counting sort -> final CSR epack + rowptr/deg ----------------
__global__ __launch_bounds__(256) void binB_k(const unsigned long long* __restrict__ stage,
                                              const int* __restrict__ gstart,
                                              unsigned long long* __restrict__ epack,
                                              int* __restrict__ rowptr, int* __restrict__ deg, int N) {
    __shared__ unsigned long long lout[2048];
    __shared__ int cnt[128], exc[128], cur[128];
    int b = blockIdx.x;
    int tid = threadIdx.x;
    int base = gstart[b];
    int nb = gstart[b + 1] - base;
    if (tid < 128) { cnt[tid] = 0; cur[tid] = 0; }
    __syncthreads();
    for (int i = tid; i < nb; i += 256)
        atomicAdd(&cnt[(int)((stage[base + i] >> 49) & 127)], 1);
    __syncthreads();
    if (tid < 128) exc[tid] = cnt[tid];
    __syncthreads();
    for (int off = 1; off < 128; off <<= 1) {
        int add = (tid >= off && tid < 128) ? exc[tid - off] : 0;
        __syncthreads();
        if (tid < 128) exc[tid] += add;
        __syncthreads();
    }
    int node0 = b * 128;
    if (tid < 128) {
        exc[tid] -= cnt[tid];  // exclusive
        int node = node0 + tid;
        if (node < N) { deg[node] = cnt[tid]; rowptr[node] = base + exc[tid]; }
    }
    __syncthreads();
    for (int i = tid; i < nb; i += 256) {
        unsigned long long v = stage[base + i];
        int dl = (int)((v >> 49) & 127);
        unsigned int src = (unsigned int)((v >> 32) & 0x1FFFF);
        unsigned int wb = (unsigned int)v;
        int pos = exc[dl] + atomicAdd(&cur[dl], 1);
        unsigned long long outv = ((unsigned long long)wb << 32) | src;
        if (pos < 2048) lout[pos] = outv;
        else epack[base + pos] = outv;
    }
    __syncthreads();
    int lim = min(nb, 2048);
    for (int i = tid; i < lim; i += 256)
        epack[base + i] = lout[i];
}

// ---------------- agg1 (8-way row-split): outb[n,:] = bf16(relu(sum_j w_j*hb[src_j,:])) ----------------
// Wave per node; lane = slot(0..7)*8 + dimg(0..7). Each lane gathers uint4
// (8 bf16, 16B); 8 edges in flight per wave; slot-group's 8 lanes cover the
// full 128B row contiguously. Reduce across slots: 3 shfl_xor steps.
__global__ __launch_bounds__(256) void agg1_k(const unsigned short* __restrict__ hb,
                                              const int* __restrict__ rowptr, const int* __restrict__ deg,
                                              const unsigned long long* __restrict__ epack,
                                              unsigned short* __restrict__ outb, int N) {
    int node = blockIdx.x * 4 + (threadIdx.x >> 6);
    if (node >= N) return;
    int lane = threadIdx.x & 63;
    int slot = lane >> 3;   // 0..7
    int dimg = lane & 7;    // 0..7 (8 dims each)
    int start = rowptr[node];
    int cnt = deg[node];
    float a[8];
#pragma unroll
    for (int q = 0; q < 8; ++q) a[q] = 0.f;
    for (int j = slot; j < cnt; j += 8) {
        unsigned long long p = epack[start + j];
        float w = __uint_as_float((unsigned int)(p >> 32));
        unsigned int src = (unsigned int)p;
        uint4 v = *reinterpret_cast<const uint4*>(hb + (size_t)src * H_DIM + dimg * 8);
        a[0] = fmaf(w, __uint_as_float(v.x << 16), a[0]);
        a[1] = fmaf(w, __uint_as_float(v.x & 0xffff0000u), a[1]);
        a[2] = fmaf(w, __uint_as_float(v.y << 16), a[2]);
        a[3] = fmaf(w, __uint_as_float(v.y & 0xffff0000u), a[3]);
        a[4] = fmaf(w, __uint_as_float(v.z << 16), a[4]);
        a[5] = fmaf(w, __uint_as_float(v.z & 0xffff0000u), a[5]);
        a[6] = fmaf(w, __uint_as_float(v.w << 16), a[6]);
        a[7] = fmaf(w, __uint_as_float(v.w & 0xffff0000u), a[7]);
    }
#pragma unroll
    for (int q = 0; q < 8; ++q) {
        a[q] += __shfl_xor(a[q], 8);
        a[q] += __shfl_xor(a[q], 16);
        a[q] += __shfl_xor(a[q], 32);
    }
    if (slot == 0) {
        uint4 o;
        o.x = (unsigned int)f2bf(fmaxf(a[0], 0.f)) | ((unsigned int)f2bf(fmaxf(a[1], 0.f)) << 16);
        o.y = (unsigned int)f2bf(fmaxf(a[2], 0.f)) | ((unsigned int)f2bf(fmaxf(a[3], 0.f)) << 16);
        o.z = (unsigned int)f2bf(fmaxf(a[4], 0.f)) | ((unsigned int)f2bf(fmaxf(a[5], 0.f)) << 16);
        o.w = (unsigned int)f2bf(fmaxf(a[6], 0.f)) | ((unsigned int)f2bf(fmaxf(a[7], 0.f)) << 16);
        *reinterpret_cast<uint4*>(outb + (size_t)node * H_DIM + dimg * 8) = o;
    }
}

// ---------------- aggv: u[n] = sum_j w_j * uz[src_j]  (thread per node, float4) ----------------
__global__ __launch_bounds__(256) void aggv_k(const float4* __restrict__ uz,
                                              const int* __restrict__ rowptr, const int* __restrict__ deg,
                                              const unsigned long long* __restrict__ epack,
                                              float4* __restrict__ u, int N) {
    int node = blockIdx.x * 256 + threadIdx.x;
    if (node >= N) return;
    int start = rowptr[node];
    int cnt = deg[node];
    float4 acc = make_float4(0.f, 0.f, 0.f, 0.f);
    int j = 0;
    for (; j + 3 < cnt; j += 4) {
#pragma unroll
        for (int q = 0; q < 4; ++q) {
            unsigned long long p = epack[start + j + q];
            float w = __uint_as_float((unsigned int)(p >> 32));
            float4 v = uz[(unsigned int)p];
            acc.x = fmaf(w, v.x, acc.x);
            acc.y = fmaf(w, v.y, acc.y);
            acc.z = fmaf(w, v.z, acc.z);
            acc.w = fmaf(w, v.w, acc.w);
        }
    }
    for (; j < cnt; ++j) {
        unsigned long long p = epack[start + j];
        float w = __uint_as_float((unsigned int)(p >> 32));
        float4 v = uz[(unsigned int)p];
        acc.x = fmaf(w, v.x, acc.x);
        acc.y = fmaf(w, v.y, acc.y);
        acc.z = fmaf(w, v.z, acc.z);
        acc.w = fmaf(w, v.w, acc.w);
    }
    u[node] = acc;
}

// ---------------- pair decode ----------------
__global__ __launch_bounds__(256) void pair_k(const float4* __restrict__ u,
                                              const int* __restrict__ pos,  // [2,P] flat
                                              float2* __restrict__ out, int P) {
    int p = blockIdx.x * 256 + threadIdx.x;
    if (p >= P) return;
    int s = pos[p];
    int t = pos[P + p];
    float4 us = u[s];
    float4 ut = u[t];
    union { float f[2]; unsigned long long v; } o;
    o.f[0] = us.x + ut.z;
    o.f[1] = us.y + ut.w;
    __builtin_nontemporal_store(o.v, reinterpret_cast<unsigned long long*>(&out[p]));
}

extern "C" void kernel_launch(void* const* d_in, const int* in_sizes, int n_in,
                              void* d_out, int out_size, void* d_ws, size_t ws_size,
                              hipStream_t stream) {
    const float* x    = (const float*)d_in[0];
    const int*   ei   = (const int*)d_in[1];    // [2,E]
    const float* ew   = (const float*)d_in[2];  // [E]
    const int*   pos  = (const int*)d_in[3];    // [2,P]
    const float* W1   = (const float*)d_in[4];  // [128,64]
    const float* W2   = (const float*)d_in[5];  // [64,64]
    const float* Wlin = (const float*)d_in[6];  // [2,128]
    float* out = (float*)d_out;

    const int N = in_sizes[0] / F_IN;      // 100000
    const int E = in_sizes[2];             // 1000000
    const int P = in_sizes[3] / 2;         // 500000
    const int nbuck = (N + 127) / 128;     // 782

    // workspace layout (bytes)
    char* ws = (char*)d_ws;
    const size_t rowBF = (size_t)N * H_DIM * sizeof(unsigned short);  // 12.8 MB
    unsigned short* hb   = (unsigned short*)ws;                // gemm1 out (bf16)
    unsigned short* a1b  = (unsigned short*)(ws + rowBF);      // relu(agg1) (bf16)
    float4*         uz   = (float4*)(ws + 2 * rowBF);          // N float4
    float4*         u    = uz + N;                             // N float4
    unsigned long long* epack = (unsigned long long*)((char*)(u + N));
    unsigned long long* stage = epack + E;
    int* ghist   = (int*)(stage + E);
    int* gstart  = ghist + NBUCK_MAX;          // nbuck+1
    int* gcursor = gstart + NBUCK_MAX + 1;
    int* rowptr  = gcursor + NBUCK_MAX;
    int* deg     = rowptr + N;
    size_t wf_off = (((size_t)((char*)(deg + N) - ws)) + 15) & ~(size_t)15;
    unsigned short* wf1 = (unsigned short*)(ws + wf_off);      // 16 KB
    unsigned short* wf2 = wf1 + 4 * 4 * 64 * 8;                // 8 KB

    // weight prepack (tiny)
    prepack_k<<<4, 256, 0, stream>>>(W1, wf1, F_IN);
    prepack_k<<<2, 256, 0, stream>>>(W2, wf2, H_DIM);

    // conv1 matmul (x f32 -> bf16 in-register) -> hb
    gemm1_k<<<(N + 63) / 64, 256, 0, stream>>>(x, wf1, hb, N);

    // binning sort -> CSR (epack, rowptr, deg)
    hipMemsetAsync(ghist, 0, (size_t)nbuck * sizeof(int), stream);
    ghist_k<<<(E + 8191) / 8192, 256, 0, stream>>>(ei, ghist, E, nbuck);
    gscan_k<<<1, 256, 0, stream>>>(ghist, gstart, gcursor, nbuck, E);
    binA_k<<<(E + 4095) / 4096, 256, 0, stream>>>(ei, ew, gcursor, stage, E, nbuck);
    binB_k<<<nbuck, 256, 0, stream>>>(stage, gstart, epack, rowptr, deg, N);

    // agg1: hb -> a1b (bf16, relu fused)
    agg1_k<<<(N + 3) / 4, 256, 0, stream>>>(hb, rowptr, deg, epack, a1b, N);
    // conv2 matmul + fused projection: a1b -> uz
    gemm2v_k<<<(N + 63) / 64, 256, 0, stream>>>(a1b, wf2, Wlin, uz, N);
    // agg2 on projected vectors: uz -> u
    aggv_k<<<(N + 255) / 256, 256, 0, stream>>>(uz, rowptr, deg, epack, u, N);
    // pair decode
    pair_k<<<(P + 255) / 256, 256, 0, stream>>>(u, pos, (float2*)out, P);
}